// Round 12
// baseline (434.146 us; speedup 1.0000x reference)
//
#include <hip/hip_runtime.h>
#include <cstdint>
#include <cstddef>

#define IN_CH 256

constexpr float BN_EPS = 1e-5f;

using u16x4 = __attribute__((ext_vector_type(4))) unsigned short;
using u16x8 = __attribute__((ext_vector_type(8))) unsigned short;
using bf16x8 = __attribute__((ext_vector_type(8))) short;
using f32x4 = __attribute__((ext_vector_type(4))) float;

#if defined(__has_builtin)
#if __has_builtin(__builtin_amdgcn_make_buffer_rsrc) && \
    __has_builtin(__builtin_amdgcn_raw_buffer_load_b32)
#define USE_BUFLOAD 1
#endif
#endif
#ifndef USE_BUFLOAD
#define USE_BUFLOAD 0
#endif

__device__ __forceinline__ unsigned short f2bf_rne(float x) {
  unsigned u = __builtin_bit_cast(unsigned, x);
  unsigned r = u + 0x7FFFu + ((u >> 16) & 1u);
  return (unsigned short)(r >> 16);
}
__device__ __forceinline__ float bf2f(unsigned short h) {
  unsigned u = ((unsigned)h) << 16;
  return __builtin_bit_cast(float, u);
}
__device__ __forceinline__ float lo16f(unsigned u) {
  return __builtin_bit_cast(float, u << 16);
}
__device__ __forceinline__ float hi16f(unsigned u) {
  return __builtin_bit_cast(float, u & 0xffff0000u);
}

// ================= CSR build: bucketed counting sort, padded-to-8 =================
// pack = (dst & 255) << 17 | src   (src < 2^17)
// srcs holds BYTE offsets (row * 32); node sections padded to multiple of 8
// edges with offset N*32 (zeroed row). Per-bucket reserve for padding: 2048.

#define NBK_MAX 400
#define BKT_RSV 2048

__global__ __launch_bounds__(256) void bucket_hist(const int* __restrict__ dst,
                                                   int* __restrict__ bcnt, int E, int nbk) {
  __shared__ int c[NBK_MAX];
  for (int j = threadIdx.x; j < nbk; j += 256) c[j] = 0;
  __syncthreads();
  for (int i = blockIdx.x * 256 + threadIdx.x; i < E; i += gridDim.x * 256)
    atomicAdd(&c[dst[i] >> 8], 1);
  __syncthreads();
  for (int j = threadIdx.x; j < nbk; j += 256)
    if (c[j]) atomicAdd(&bcnt[j], c[j]);
}

__global__ void bucket_scan(const int* __restrict__ bcnt, int* __restrict__ boff,
                            int* __restrict__ gcur, int E, int nbk) {
  __shared__ int lds[512];
  int t = threadIdx.x;
  int v = (t < nbk) ? bcnt[t] : 0;
  lds[t] = v;
  __syncthreads();
  for (int s = 1; s < 512; s <<= 1) {
    int x = (t >= s) ? lds[t - s] : 0;
    __syncthreads();
    lds[t] += x;
    __syncthreads();
  }
  if (t < nbk) {
    boff[t] = lds[t] - v;
    gcur[t] = lds[t] - v;
  }
  if (t == 0) boff[nbk] = E;
}

__global__ __launch_bounds__(256) void partition(const int* __restrict__ src,
                                                 const int* __restrict__ dst,
                                                 int* __restrict__ gcur,
                                                 unsigned* __restrict__ part, int E, int nbk) {
  __shared__ int cnt[NBK_MAX];
  __shared__ int base[NBK_MAX];
  const int t = threadIdx.x;
  for (int j = t; j < nbk; j += 256) cnt[j] = 0;
  __syncthreads();
  const int e0 = blockIdx.x * 4096;
  unsigned mypk[16];
  int mybk[16];
#pragma unroll
  for (int u = 0; u < 16; ++u) {
    int e = e0 + u * 256 + t;
    if (e < E) {
      int d = dst[e];
      mypk[u] = (unsigned)src[e] | ((unsigned)(d & 255) << 17);
      mybk[u] = d >> 8;
      atomicAdd(&cnt[mybk[u]], 1);
    } else {
      mybk[u] = -1;
    }
  }
  __syncthreads();
  for (int j = t; j < nbk; j += 256) {
    int c = cnt[j];
    base[j] = c ? atomicAdd(&gcur[j], c) : 0;
    cnt[j] = 0;
  }
  __syncthreads();
#pragma unroll
  for (int u = 0; u < 16; ++u) {
    if (mybk[u] >= 0) {
      int r = atomicAdd(&cnt[mybk[u]], 1);
      part[base[mybk[u]] + r] = mypk[u];
    }
  }
}

__global__ __launch_bounds__(256) void bucket_csr(const unsigned* __restrict__ part,
                                                  const int* __restrict__ boff,
                                                  int* __restrict__ offs,
                                                  unsigned char* __restrict__ nbat,
                                                  int* __restrict__ srcs,
                                                  float* __restrict__ dinv, int N, int E) {
  __shared__ unsigned pk[8192];
  __shared__ int ssrc[8192 + BKT_RSV];
  __shared__ int cnt[256];
  __shared__ int offl[256];
  __shared__ int cur[256];
  const int b = blockIdx.x;
  const int t = threadIdx.x;
  const int e0 = boff[b];
  int ne = boff[b + 1] - e0;
  if (ne > 8192) ne = 8192;
  const int e0p = e0 + b * BKT_RSV;
  cnt[t] = 0;
  __syncthreads();
  for (int i = t; i < ne; i += 256) {
    unsigned v = part[e0 + i];
    pk[i] = v;
    atomicAdd(&cnt[v >> 17], 1);
  }
  __syncthreads();
  const int deg = cnt[t];
  const int degp = (deg + 7) & ~7;
  offl[t] = degp;
  __syncthreads();
  for (int s = 1; s < 256; s <<= 1) {
    int x = (t >= s) ? offl[t - s] : 0;
    __syncthreads();
    offl[t] += x;
    __syncthreads();
  }
  const int exclp = offl[t] - degp;
  const int totalp = offl[255];
  cur[t] = exclp;
  __syncthreads();
  // pre-fill padded span with zero-row offset, then scatter real edges
  for (int i = t; i < totalp; i += 256) ssrc[i] = N << 5;
  __syncthreads();
  for (int i = t; i < ne; i += 256) {
    unsigned p = pk[i];
    int dl = p >> 17;
    int r = atomicAdd(&cur[dl], 1);
    ssrc[r] = (int)((p & 0x1FFFFu) << 5);
  }
  __syncthreads();
  for (int i = t; i < totalp; i += 256) srcs[e0p + i] = ssrc[i];
  int node = b * 256 + t;
  if (node < N) {
    offs[node] = e0p + exclp;
    nbat[node] = (unsigned char)(degp >> 3);
    dinv[node] = rsqrtf((float)(deg + 1));
  }
}

// zero row N of each of the 8 g-slices (pad gathers land here)
__global__ void zrow(unsigned short* g, int N) {
  int i = threadIdx.x;
  if (i < 8 * 16) g[((size_t)(i >> 4) * (N + 1) + N) * 16 + (i & 15)] = 0;
}

// ================= weight prep: transpose + hi/lo bf16 split =================

__global__ void wprep(const float* __restrict__ W, unsigned short* __restrict__ hi,
                      unsigned short* __restrict__ lo, int K, int N) {
  int i = blockIdx.x * 256 + threadIdx.x;
  if (i >= K * N) return;
  int k = i / N, n = i - k * N;
  float v = W[i];
  unsigned short h = f2bf_rne(v);
  hi[(size_t)n * K + k] = h;
  lo[(size_t)n * K + k] = f2bf_rne(v - bf2f(h));
}

// ================= MFMA GEMM =================
// A: fp32 (ABF16=false) or bf16 row-major (ABF16=true).
// Out (bf16) COLUMN-SLICED: [SLICES][M+1][16] (row M is the zero pad row)

template <int K, int BN, int SLICES, bool BNRELU, bool ABF16>
__global__ __launch_bounds__(256) void mfma_gemm(const void* __restrict__ Av,
                                                 const unsigned short* __restrict__ Bt_hi,
                                                 const unsigned short* __restrict__ Bt_lo,
                                                 const float* __restrict__ ss,
                                                 const float* __restrict__ dinv,
                                                 unsigned short* __restrict__ Out, int M) {
  constexpr int BM = 128;
  constexpr int CS = BN / SLICES;  // = 16
  __shared__ unsigned short Ah[BM * 32];
  __shared__ unsigned short Al[BM * 32];
  __shared__ unsigned short Bh[BN * 32];
  __shared__ unsigned short Bl[BN * 32];

  const int tid = threadIdx.x;
  const int wave = tid >> 6;
  const int lane = tid & 63;
  const int lg = lane >> 4;
  const int lr = lane & 15;
  const int row0 = blockIdx.x * BM;

  f32x4 acc[2][BN / 16];
#pragma unroll
  for (int f = 0; f < 2; ++f)
#pragma unroll
    for (int j = 0; j < BN / 16; ++j) acc[f][j] = (f32x4){0.f, 0.f, 0.f, 0.f};

  for (int k0 = 0; k0 < K; k0 += 32) {
    __syncthreads();
#pragma unroll
    for (int it = 0; it < 4; ++it) {
      int m = it * 32 + (tid >> 3);
      int c2 = tid & 7;
      float vv[4] = {0.f, 0.f, 0.f, 0.f};
      if constexpr (ABF16) {
        if (row0 + m < M) {
          u16x4 r = *(const u16x4*)&(
              (const unsigned short*)Av)[(size_t)(row0 + m) * K + k0 + c2 * 4];
#pragma unroll
          for (int i = 0; i < 4; ++i) vv[i] = bf2f(r[i]);
        }
      } else {
        if (row0 + m < M) {
          float4 v = *(const float4*)&((const float*)Av)[(size_t)(row0 + m) * K + k0 + c2 * 4];
          vv[0] = v.x;
          vv[1] = v.y;
          vv[2] = v.z;
          vv[3] = v.w;
        }
      }
      if constexpr (BNRELU) {
        int kk = k0 + c2 * 4;
        float4 sc = *(const float4*)&ss[kk];
        float4 sh = *(const float4*)&ss[K + kk];
        vv[0] = fmaxf(0.f, fmaf(vv[0], sc.x, sh.x));
        vv[1] = fmaxf(0.f, fmaf(vv[1], sc.y, sh.y));
        vv[2] = fmaxf(0.f, fmaf(vv[2], sc.z, sh.z));
        vv[3] = fmaxf(0.f, fmaf(vv[3], sc.w, sh.w));
      }
      u16x4 h4, l4;
#pragma unroll
      for (int i = 0; i < 4; ++i) {
        unsigned short h = f2bf_rne(vv[i]);
        h4[i] = h;
        l4[i] = f2bf_rne(vv[i] - bf2f(h));
      }
      int pr = (m >> 1) & 3;
      int base = m * 32 + (((c2 >> 1) ^ pr) * 8) + (c2 & 1) * 4;
      *(u16x4*)&Ah[base] = h4;
      *(u16x4*)&Al[base] = l4;
    }
#pragma unroll
    for (int it = 0; it < BN / 64; ++it) {
      int n = it * 64 + (tid >> 2);
      int c = tid & 3;
      int pr = (n >> 1) & 3;
      int base = n * 32 + ((c ^ pr) * 8);
      *(u16x8*)&Bh[base] = *(const u16x8*)&Bt_hi[(size_t)n * K + k0 + c * 8];
      *(u16x8*)&Bl[base] = *(const u16x8*)&Bt_lo[(size_t)n * K + k0 + c * 8];
    }
    __syncthreads();

    bf16x8 afh[2], afl[2];
#pragma unroll
    for (int f = 0; f < 2; ++f) {
      int m = wave * 32 + f * 16 + lr;
      int pr = (m >> 1) & 3;
      int base = m * 32 + ((lg ^ pr) * 8);
      afh[f] = *(const bf16x8*)&Ah[base];
      afl[f] = *(const bf16x8*)&Al[base];
    }
#pragma unroll
    for (int j = 0; j < BN / 16; ++j) {
      int n = j * 16 + lr;
      int pr = (n >> 1) & 3;
      int base = n * 32 + ((lg ^ pr) * 8);
      bf16x8 bh = *(const bf16x8*)&Bh[base];
      bf16x8 bl = *(const bf16x8*)&Bl[base];
#pragma unroll
      for (int f = 0; f < 2; ++f) {
        acc[f][j] = __builtin_amdgcn_mfma_f32_16x16x32_bf16(afh[f], bh, acc[f][j], 0, 0, 0);
        acc[f][j] = __builtin_amdgcn_mfma_f32_16x16x32_bf16(afl[f], bh, acc[f][j], 0, 0, 0);
        acc[f][j] = __builtin_amdgcn_mfma_f32_16x16x32_bf16(afh[f], bl, acc[f][j], 0, 0, 0);
      }
    }
  }

  // epilogue: scale by dinv, store bf16 column-sliced [SLICES][M+1][CS]
#pragma unroll
  for (int f = 0; f < 2; ++f) {
#pragma unroll
    for (int r4 = 0; r4 < 4; ++r4) {
      int r = row0 + wave * 32 + f * 16 + lg * 4 + r4;
      if (r >= M) continue;
      float dv = dinv[r];
#pragma unroll
      for (int j = 0; j < BN / 16; ++j) {
        int c = j * 16 + lr;
        int slice = c / CS;
        int wi = c % CS;
        Out[((size_t)slice * (M + 1) + r) * CS + wi] = f2bf_rne(acc[f][j][r4] * dv);
      }
    }
  }
}

// ================= sliced aggregation: padded batches, buffer gathers, 2-deep =================
// g column-sliced [NSLICE][N+1][16] bf16 (row stride 32B, row N zeroed).
// Block = (slice, 128-node chunk), 4 waves; 8-lane groups own one node.
// Unconditional 8-edge batches (nbat[node] count); batch b+1 gathers and batch
// b+2 srcs issued before consuming batch b (16 loads in flight / group).
// Buffer-descriptor gathers: 32-bit voffset, OOB speculative reads return 0.

template <int C, int NSLICE, bool STATS, bool FINAL>
__global__ __launch_bounds__(256) void agg_slice(const unsigned short* __restrict__ g,
                                                 const int* __restrict__ offs,
                                                 const unsigned char* __restrict__ nbat,
                                                 const int* __restrict__ srcsb,
                                                 const float* __restrict__ dinv,
                                                 const float* __restrict__ bias,
                                                 void* __restrict__ outv,
                                                 float* __restrict__ stat, int N) {
  constexpr int CS = C / NSLICE;  // 16
  constexpr int LPE = 8;
  const int s = blockIdx.x;  // slice
  const int w = threadIdx.x >> 6;
  const int lane = threadIdx.x & 63;
  const int gi = lane >> 3;
  const int ch2 = lane & 7;
  const unsigned choff = (unsigned)ch2 * 4;
  const unsigned sliceBytes = (unsigned)(N + 1) * 32;
  const char* sbase = (const char*)g + (size_t)s * sliceBytes;
  const int cb = ch2 * 2;

#if USE_BUFLOAD
  auto rsrc =
      __builtin_amdgcn_make_buffer_rsrc((void*)sbase, (short)0, (int)sliceBytes, 0x00020000);
  auto GATHER = [&](unsigned off) -> unsigned {
    return (unsigned)__builtin_amdgcn_raw_buffer_load_b32(rsrc, (int)off, 0, 0);
  };
#else
  auto GATHER = [&](unsigned off) -> unsigned {
    return (off + 4 <= sliceBytes) ? *(const unsigned*)(sbase + off) : 0u;
  };
#endif

  float sx = 0.f, sy = 0.f, qx = 0.f, qy = 0.f;

#pragma unroll
  for (int it = 0; it < 4; ++it) {
    int node = blockIdx.y * 128 + it * 32 + w * 8 + gi;
    if (node < N) {
      unsigned u = *(const unsigned*)(sbase + (size_t)node * 32 + choff);
      float ax = lo16f(u);
      float ay = hi16f(u);

      const int base = offs[node];
      const int nb = nbat[node];
      unsigned sA[8], sB[8], gA[8], gB[8];
#pragma unroll
      for (int j = 0; j < 8; ++j) sA[j] = (unsigned)srcsb[base + j] | choff;
#pragma unroll
      for (int j = 0; j < 8; ++j) gA[j] = GATHER(sA[j]);
#pragma unroll
      for (int j = 0; j < 8; ++j) sB[j] = (unsigned)srcsb[base + 8 + j] | choff;

      for (int b = 0; b < nb; ++b) {
#pragma unroll
        for (int j = 0; j < 8; ++j) gB[j] = GATHER(sB[j]);  // batch b+1 (spec ok)
#pragma unroll
        for (int j = 0; j < 8; ++j)
          sB[j] = (unsigned)srcsb[base + (b + 2) * 8 + j] | choff;  // batch b+2
#pragma unroll
        for (int j = 0; j < 8; ++j) {  // consume batch b
          ax += lo16f(gA[j]);
          ay += hi16f(gA[j]);
        }
#pragma unroll
        for (int j = 0; j < 8; ++j) gA[j] = gB[j];
      }

      float dv = dinv[node];
      float ox = ax * dv, oy = ay * dv;
      if constexpr (FINAL) {
        ox += bias[s * CS + cb];
        oy += bias[s * CS + cb + 1];
        *(float2*)&((float*)outv)[(size_t)node * C + s * CS + cb] = (float2){ox, oy};
      } else {
        unsigned ob = (unsigned)f2bf_rne(ox) | ((unsigned)f2bf_rne(oy) << 16);
        ((unsigned*)outv)[((size_t)node * C + s * CS + cb) >> 1] = ob;
      }
      if constexpr (STATS) {
        sx += ox;
        sy += oy;
        qx += ox * ox;
        qy += oy * oy;
      }
    }
  }

  if constexpr (STATS) {
    __shared__ float red[256][4];
    red[threadIdx.x][0] = sx;
    red[threadIdx.x][1] = sy;
    red[threadIdx.x][2] = qx;
    red[threadIdx.x][3] = qy;
    __syncthreads();
    if (threadIdx.x < LPE) {
      float a0 = 0.f, a1 = 0.f, a2 = 0.f, a3 = 0.f;
      for (int k = threadIdx.x; k < 256; k += LPE) {
        a0 += red[k][0];
        a1 += red[k][1];
        a2 += red[k][2];
        a3 += red[k][3];
      }
      atomicAdd(&stat[s * CS + threadIdx.x * 2], a0);
      atomicAdd(&stat[s * CS + threadIdx.x * 2 + 1], a1);
      atomicAdd(&stat[C + s * CS + threadIdx.x * 2], a2);
      atomicAdd(&stat[C + s * CS + threadIdx.x * 2 + 1], a3);
    }
  }
}

// ================= BN finalize =================

template <int C>
__global__ void bn_finalize(const float* __restrict__ stat, const float* __restrict__ gamma,
                            const float* __restrict__ beta, float* __restrict__ ss, int N) {
  int c = threadIdx.x;
  if (c >= C) return;
  float mu = stat[c] / (float)N;
  float var = stat[C + c] / (float)N - mu * mu;
  float rs = rsqrtf(var + BN_EPS);
  float sc = gamma[c] * rs;
  ss[c] = sc;
  ss[C + c] = beta[c] - mu * sc;
}

// ================= launch =================

extern "C" void kernel_launch(void* const* d_in, const int* in_sizes, int n_in, void* d_out,
                              int out_size, void* d_ws, size_t ws_size, hipStream_t stream) {
  const float* x = (const float*)d_in[0];
  const int* ei = (const int*)d_in[1];
  const float* W1 = (const float*)d_in[2];
  const float* gamma1 = (const float*)d_in[4];
  const float* beta1 = (const float*)d_in[5];
  const float* W2 = (const float*)d_in[6];
  const float* gamma2 = (const float*)d_in[8];
  const float* beta2 = (const float*)d_in[9];
  const float* W3 = (const float*)d_in[10];
  const float* b3 = (const float*)d_in[11];
  float* out = (float*)d_out;

  const int N = in_sizes[0] / IN_CH;  // 100000
  const int E = in_sizes[1] / 2;      // 1600000
  const int* e_src = ei;
  const int* e_dst = ei + E;
  const int nbk = (N + 255) >> 8;  // 391

  char* ws = (char*)d_ws;
  size_t off = 0;
  auto alloc = [&](size_t bytes) {
    size_t r = off;
    off += (bytes + 1023) & ~(size_t)1023;
    return r;
  };
  int* bcnt = (int*)(ws + alloc(NBK_MAX * 4));
  int* boff = (int*)(ws + alloc((NBK_MAX + 1) * 4));
  int* gcur = (int*)(ws + alloc(NBK_MAX * 4));
  unsigned* part = (unsigned*)(ws + alloc((size_t)E * 4));
  int* offs = (int*)(ws + alloc((size_t)(N + 1) * 4));
  int* srcs = (int*)(ws + alloc(((size_t)E + (size_t)nbk * BKT_RSV + 64) * 4));
  unsigned char* nbat = (unsigned char*)(ws + alloc((size_t)N));
  float* dinv = (float*)(ws + alloc((size_t)N * 4));
  unsigned short* Wt1h = (unsigned short*)(ws + alloc(256 * 128 * 2));
  unsigned short* Wt1l = (unsigned short*)(ws + alloc(256 * 128 * 2));
  unsigned short* Wt2h = (unsigned short*)(ws + alloc(128 * 64 * 2));
  unsigned short* Wt2l = (unsigned short*)(ws + alloc(128 * 64 * 2));
  unsigned short* Wt3h = (unsigned short*)(ws + alloc(64 * 64 * 2));
  unsigned short* Wt3l = (unsigned short*)(ws + alloc(64 * 64 * 2));
  float* stat1 = (float*)(ws + alloc(256 * 4));
  float* stat2 = (float*)(ws + alloc(128 * 4));
  float* ss1 = (float*)(ws + alloc(256 * 4));
  float* ss2 = (float*)(ws + alloc(128 * 4));
  unsigned short* g =
      (unsigned short*)(ws + alloc((size_t)8 * (N + 1) * 16 * 2));  // sliced GEMM out
  unsigned short* hb = (unsigned short*)(ws + alloc((size_t)N * 128 * 2));  // row-major agg out

  hipMemsetAsync(bcnt, 0, NBK_MAX * 4, stream);
  hipMemsetAsync(stat1, 0, 256 * 4, stream);
  hipMemsetAsync(stat2, 0, 128 * 4, stream);

  bucket_hist<<<2048, 256, 0, stream>>>(e_dst, bcnt, E, nbk);
  bucket_scan<<<1, 512, 0, stream>>>(bcnt, boff, gcur, E, nbk);
  partition<<<(E + 4095) / 4096, 256, 0, stream>>>(e_src, e_dst, gcur, part, E, nbk);
  bucket_csr<<<nbk, 256, 0, stream>>>(part, boff, offs, nbat, srcs, dinv, N, E);
  zrow<<<1, 128, 0, stream>>>(g, N);

  wprep<<<(256 * 128 + 255) / 256, 256, 0, stream>>>(W1, Wt1h, Wt1l, 256, 128);
  wprep<<<(128 * 64 + 255) / 256, 256, 0, stream>>>(W2, Wt2h, Wt2l, 128, 64);
  wprep<<<(64 * 64 + 255) / 256, 256, 0, stream>>>(W3, Wt3h, Wt3l, 64, 64);

  const int gM = (N + 127) / 128;   // 782
  const int nch = (N + 127) / 128;  // node chunks
  const dim3 gAgg1(8, nch);         // layer 1: 8 slices
  const dim3 gAgg2(4, nch);         // layers 2/3: 4 slices

  // ---- layer 1: 256 -> 128 ----
  mfma_gemm<256, 128, 8, false, false><<<gM, 256, 0, stream>>>(x, Wt1h, Wt1l, nullptr, dinv, g,
                                                               N);
  agg_slice<128, 8, true, false><<<gAgg1, 256, 0, stream>>>(g, offs, nbat, srcs, dinv, nullptr,
                                                            hb, stat1, N);
  bn_finalize<128><<<1, 128, 0, stream>>>(stat1, gamma1, beta1, ss1, N);

  // ---- layer 2: 128 -> 64 (BN+ReLU fused into A staging, A = bf16 hb) ----
  mfma_gemm<128, 64, 4, true, true><<<gM, 256, 0, stream>>>(hb, Wt2h, Wt2l, ss1, dinv, g, N);
  agg_slice<64, 4, true, false><<<gAgg2, 256, 0, stream>>>(g, offs, nbat, srcs, dinv, nullptr,
                                                           hb, stat2, N);
  bn_finalize<64><<<1, 64, 0, stream>>>(stat2, gamma2, beta2, ss2, N);

  // ---- layer 3: 64 -> 64 ----
  mfma_gemm<64, 64, 4, true, true><<<gM, 256, 0, stream>>>(hb, Wt3h, Wt3l, ss2, dinv, g, N);
  agg_slice<64, 4, false, true><<<gAgg2, 256, 0, stream>>>(g, offs, nbat, srcs, dinv, b3, out,
                                                           nullptr, N);
}

// Round 13
// 426.668 us; speedup vs baseline: 1.0175x; 1.0175x over previous
//
#include <hip/hip_runtime.h>
#include <cstdint>
#include <cstddef>

#define IN_CH 256

constexpr float BN_EPS = 1e-5f;

using u16x4 = __attribute__((ext_vector_type(4))) unsigned short;
using u16x8 = __attribute__((ext_vector_type(8))) unsigned short;
using bf16x8 = __attribute__((ext_vector_type(8))) short;
using f32x4 = __attribute__((ext_vector_type(4))) float;

__device__ __forceinline__ unsigned short f2bf_rne(float x) {
  unsigned u = __builtin_bit_cast(unsigned, x);
  unsigned r = u + 0x7FFFu + ((u >> 16) & 1u);
  return (unsigned short)(r >> 16);
}
__device__ __forceinline__ float bf2f(unsigned short h) {
  unsigned u = ((unsigned)h) << 16;
  return __builtin_bit_cast(float, u);
}
__device__ __forceinline__ float lo16f(unsigned u) {
  return __builtin_bit_cast(float, u << 16);
}
__device__ __forceinline__ float hi16f(unsigned u) {
  return __builtin_bit_cast(float, u & 0xffff0000u);
}

// ================= CSR build: bucketed counting sort, coalesced IO =================
// pack = (dst & 255) << 17 | src   (src < 2^17)

#define NBK_MAX 400

__global__ __launch_bounds__(256) void bucket_hist(const int* __restrict__ dst,
                                                   int* __restrict__ bcnt, int E, int nbk) {
  __shared__ int c[NBK_MAX];
  for (int j = threadIdx.x; j < nbk; j += 256) c[j] = 0;
  __syncthreads();
  for (int i = blockIdx.x * 256 + threadIdx.x; i < E; i += gridDim.x * 256)
    atomicAdd(&c[dst[i] >> 8], 1);
  __syncthreads();
  for (int j = threadIdx.x; j < nbk; j += 256)
    if (c[j]) atomicAdd(&bcnt[j], c[j]);
}

__global__ void bucket_scan(const int* __restrict__ bcnt, int* __restrict__ boff,
                            int* __restrict__ gcur, int E, int nbk) {
  __shared__ int lds[512];
  int t = threadIdx.x;
  int v = (t < nbk) ? bcnt[t] : 0;
  lds[t] = v;
  __syncthreads();
  for (int s = 1; s < 512; s <<= 1) {
    int x = (t >= s) ? lds[t - s] : 0;
    __syncthreads();
    lds[t] += x;
    __syncthreads();
  }
  if (t < nbk) {
    boff[t] = lds[t] - v;
    gcur[t] = lds[t] - v;
  }
  if (t == 0) boff[nbk] = E;
}

__global__ __launch_bounds__(256) void partition(const int* __restrict__ src,
                                                 const int* __restrict__ dst,
                                                 int* __restrict__ gcur,
                                                 unsigned* __restrict__ part, int E, int nbk) {
  __shared__ int cnt[NBK_MAX];
  __shared__ int base[NBK_MAX];
  const int t = threadIdx.x;
  for (int j = t; j < nbk; j += 256) cnt[j] = 0;
  __syncthreads();
  const int e0 = blockIdx.x * 4096;
  unsigned mypk[16];
  int mybk[16];
#pragma unroll
  for (int u = 0; u < 16; ++u) {
    int e = e0 + u * 256 + t;
    if (e < E) {
      int d = dst[e];
      mypk[u] = (unsigned)src[e] | ((unsigned)(d & 255) << 17);
      mybk[u] = d >> 8;
      atomicAdd(&cnt[mybk[u]], 1);
    } else {
      mybk[u] = -1;
    }
  }
  __syncthreads();
  for (int j = t; j < nbk; j += 256) {
    int c = cnt[j];
    base[j] = c ? atomicAdd(&gcur[j], c) : 0;
    cnt[j] = 0;
  }
  __syncthreads();
#pragma unroll
  for (int u = 0; u < 16; ++u) {
    if (mybk[u] >= 0) {
      int r = atomicAdd(&cnt[mybk[u]], 1);
      part[base[mybk[u]] + r] = mypk[u];
    }
  }
}

// emits srcs as BYTE OFFSETS (row * 32, CS=16 bf16 rows) for the agg kernels
__global__ __launch_bounds__(256) void bucket_csr(const unsigned* __restrict__ part,
                                                  const int* __restrict__ boff,
                                                  int* __restrict__ offs, int* __restrict__ srcs,
                                                  float* __restrict__ dinv, int N, int E) {
  __shared__ unsigned pk[8192];
  __shared__ int ssrc[8192];
  __shared__ int cnt[256];
  __shared__ int offl[256];
  __shared__ int cur[256];
  const int b = blockIdx.x;
  const int t = threadIdx.x;
  const int e0 = boff[b];
  int ne = boff[b + 1] - e0;
  if (ne > 8192) ne = 8192;
  cnt[t] = 0;
  __syncthreads();
  for (int i = t; i < ne; i += 256) {
    unsigned v = part[e0 + i];
    pk[i] = v;
    atomicAdd(&cnt[v >> 17], 1);
  }
  __syncthreads();
  int vv = cnt[t];
  offl[t] = vv;
  __syncthreads();
  for (int s = 1; s < 256; s <<= 1) {
    int x = (t >= s) ? offl[t - s] : 0;
    __syncthreads();
    offl[t] += x;
    __syncthreads();
  }
  int excl = offl[t] - vv;
  cur[t] = excl;
  __syncthreads();
  for (int i = t; i < ne; i += 256) {
    unsigned p = pk[i];
    int dl = p >> 17;
    int r = atomicAdd(&cur[dl], 1);
    ssrc[r] = (int)(p & 0x1FFFF) << 5;  // byte offset, row stride 32B
  }
  __syncthreads();
  for (int i = t; i < ne; i += 256) srcs[e0 + i] = ssrc[i];
  int node = b * 256 + t;
  if (node < N) {
    offs[node] = e0 + excl;
    dinv[node] = rsqrtf((float)(vv + 1));
  }
  if (b == gridDim.x - 1 && t == 0) offs[N] = E;
}

// ================= weight prep: transpose + hi/lo bf16 split =================

__global__ void wprep(const float* __restrict__ W, unsigned short* __restrict__ hi,
                      unsigned short* __restrict__ lo, int K, int N) {
  int i = blockIdx.x * 256 + threadIdx.x;
  if (i >= K * N) return;
  int k = i / N, n = i - k * N;
  float v = W[i];
  unsigned short h = f2bf_rne(v);
  hi[(size_t)n * K + k] = h;
  lo[(size_t)n * K + k] = f2bf_rne(v - bf2f(h));
}

// ================= MFMA GEMM =================
// A: fp32 (ABF16=false) or bf16 row-major (ABF16=true).
// Out (bf16) written COLUMN-SLICED: [SLICES][M][BN/SLICES]

template <int K, int BN, int SLICES, bool BNRELU, bool ABF16>
__global__ __launch_bounds__(256) void mfma_gemm(const void* __restrict__ Av,
                                                 const unsigned short* __restrict__ Bt_hi,
                                                 const unsigned short* __restrict__ Bt_lo,
                                                 const float* __restrict__ ss,
                                                 const float* __restrict__ dinv,
                                                 unsigned short* __restrict__ Out, int M) {
  constexpr int BM = 128;
  constexpr int CS = BN / SLICES;  // = 16
  __shared__ unsigned short Ah[BM * 32];
  __shared__ unsigned short Al[BM * 32];
  __shared__ unsigned short Bh[BN * 32];
  __shared__ unsigned short Bl[BN * 32];

  const int tid = threadIdx.x;
  const int wave = tid >> 6;
  const int lane = tid & 63;
  const int lg = lane >> 4;
  const int lr = lane & 15;
  const int row0 = blockIdx.x * BM;

  f32x4 acc[2][BN / 16];
#pragma unroll
  for (int f = 0; f < 2; ++f)
#pragma unroll
    for (int j = 0; j < BN / 16; ++j) acc[f][j] = (f32x4){0.f, 0.f, 0.f, 0.f};

  for (int k0 = 0; k0 < K; k0 += 32) {
    __syncthreads();
#pragma unroll
    for (int it = 0; it < 4; ++it) {
      int m = it * 32 + (tid >> 3);
      int c2 = tid & 7;
      float vv[4] = {0.f, 0.f, 0.f, 0.f};
      if constexpr (ABF16) {
        if (row0 + m < M) {
          u16x4 r = *(const u16x4*)&(
              (const unsigned short*)Av)[(size_t)(row0 + m) * K + k0 + c2 * 4];
#pragma unroll
          for (int i = 0; i < 4; ++i) vv[i] = bf2f(r[i]);
        }
      } else {
        if (row0 + m < M) {
          float4 v = *(const float4*)&((const float*)Av)[(size_t)(row0 + m) * K + k0 + c2 * 4];
          vv[0] = v.x;
          vv[1] = v.y;
          vv[2] = v.z;
          vv[3] = v.w;
        }
      }
      if constexpr (BNRELU) {
        int kk = k0 + c2 * 4;
        float4 sc = *(const float4*)&ss[kk];
        float4 sh = *(const float4*)&ss[K + kk];
        vv[0] = fmaxf(0.f, fmaf(vv[0], sc.x, sh.x));
        vv[1] = fmaxf(0.f, fmaf(vv[1], sc.y, sh.y));
        vv[2] = fmaxf(0.f, fmaf(vv[2], sc.z, sh.z));
        vv[3] = fmaxf(0.f, fmaf(vv[3], sc.w, sh.w));
      }
      u16x4 h4, l4;
#pragma unroll
      for (int i = 0; i < 4; ++i) {
        unsigned short h = f2bf_rne(vv[i]);
        h4[i] = h;
        l4[i] = f2bf_rne(vv[i] - bf2f(h));
      }
      int pr = (m >> 1) & 3;
      int base = m * 32 + (((c2 >> 1) ^ pr) * 8) + (c2 & 1) * 4;
      *(u16x4*)&Ah[base] = h4;
      *(u16x4*)&Al[base] = l4;
    }
#pragma unroll
    for (int it = 0; it < BN / 64; ++it) {
      int n = it * 64 + (tid >> 2);
      int c = tid & 3;
      int pr = (n >> 1) & 3;
      int base = n * 32 + ((c ^ pr) * 8);
      *(u16x8*)&Bh[base] = *(const u16x8*)&Bt_hi[(size_t)n * K + k0 + c * 8];
      *(u16x8*)&Bl[base] = *(const u16x8*)&Bt_lo[(size_t)n * K + k0 + c * 8];
    }
    __syncthreads();

    bf16x8 afh[2], afl[2];
#pragma unroll
    for (int f = 0; f < 2; ++f) {
      int m = wave * 32 + f * 16 + lr;
      int pr = (m >> 1) & 3;
      int base = m * 32 + ((lg ^ pr) * 8);
      afh[f] = *(const bf16x8*)&Ah[base];
      afl[f] = *(const bf16x8*)&Al[base];
    }
#pragma unroll
    for (int j = 0; j < BN / 16; ++j) {
      int n = j * 16 + lr;
      int pr = (n >> 1) & 3;
      int base = n * 32 + ((lg ^ pr) * 8);
      bf16x8 bh = *(const bf16x8*)&Bh[base];
      bf16x8 bl = *(const bf16x8*)&Bl[base];
#pragma unroll
      for (int f = 0; f < 2; ++f) {
        acc[f][j] = __builtin_amdgcn_mfma_f32_16x16x32_bf16(afh[f], bh, acc[f][j], 0, 0, 0);
        acc[f][j] = __builtin_amdgcn_mfma_f32_16x16x32_bf16(afl[f], bh, acc[f][j], 0, 0, 0);
        acc[f][j] = __builtin_amdgcn_mfma_f32_16x16x32_bf16(afh[f], bl, acc[f][j], 0, 0, 0);
      }
    }
  }

  // epilogue: scale by dinv, store bf16 column-sliced [SLICES][M][CS]
#pragma unroll
  for (int f = 0; f < 2; ++f) {
#pragma unroll
    for (int r4 = 0; r4 < 4; ++r4) {
      int r = row0 + wave * 32 + f * 16 + lg * 4 + r4;
      if (r >= M) continue;
      float dv = dinv[r];
#pragma unroll
      for (int j = 0; j < BN / 16; ++j) {
        int c = j * 16 + lr;
        int slice = c / CS;
        int wi = c % CS;
        Out[((size_t)slice * M + r) * CS + wi] = f2bf_rne(acc[f][j][r4] * dv);
      }
    }
  }
}

// ================= sliced aggregation, node-per-group (LPE=4, cached) =================
// g column-sliced [NSLICE][N][CS=16] bf16 (row stride 32B). Block = (slice, 128-node
// chunk), 4 waves. 4-lane groups own one node each (uint2 = 8B = 4 ch per lane);
// 8-edge predicated batches with next-batch srcs prefetch. srcs holds BYTE offsets.
// ALL loads/stores CACHED (NT regressed in r10: srcs sits in the dependent chain and
// must stay L2-resident). FINAL=false: out bf16 row-major; FINAL=true: fp32 (+bias).

template <int C, int NSLICE, bool STATS, bool FINAL>
__global__ __launch_bounds__(256) void agg_slice(const unsigned short* __restrict__ g,
                                                 const int* __restrict__ offs,
                                                 const int* __restrict__ srcsb,
                                                 const float* __restrict__ dinv,
                                                 const float* __restrict__ bias,
                                                 void* __restrict__ outv,
                                                 float* __restrict__ stat, int N) {
  constexpr int CS = C / NSLICE;  // 16
  constexpr int LPE = 4;          // lanes per node-group, 4ch (8B) per lane
  constexpr int NPW = 64 / LPE;   // 16 nodes per wave per iter
  constexpr int T = 2;            // 2 iters x 4 waves x 16 = 128 nodes per block
  const int s = blockIdx.x;       // slice
  const int w = threadIdx.x >> 6;
  const int lane = threadIdx.x & 63;
  const int gi = lane >> 2;
  const int ch2 = lane & 3;  // 4-channel group
  const char* lane_base = (const char*)(g + (size_t)s * N * CS) + ch2 * 8;
  const int cb = ch2 * 4;

  float ssum[4] = {0.f, 0.f, 0.f, 0.f};
  float sq[4] = {0.f, 0.f, 0.f, 0.f};

#pragma unroll
  for (int it = 0; it < T; ++it) {
    int node = blockIdx.y * 128 + it * (4 * NPW) + w * NPW + gi;
    if (node < N) {
      uint2 u0 = *(const uint2*)(lane_base + (size_t)node * (CS * 2));
      float a0 = lo16f(u0.x), a1 = hi16f(u0.x), a2 = lo16f(u0.y), a3 = hi16f(u0.y);

      const int e0 = offs[node], e1 = offs[node + 1];
      const int nb = (e1 - e0 + 7) >> 3;
      int sA[8], sB[8];
#pragma unroll
      for (int j = 0; j < 8; ++j) sA[j] = srcsb[e0 + j];  // padded alloc: safe
      for (int b = 0; b < nb; ++b) {
        const int base = e0 + b * 8;
#pragma unroll
        for (int j = 0; j < 8; ++j) sB[j] = srcsb[base + 8 + j];  // prefetch next
        uint2 uu[8];
#pragma unroll
        for (int j = 0; j < 8; ++j) {
          uu[j].x = 0u;
          uu[j].y = 0u;
          if (base + j < e1) uu[j] = *(const uint2*)(lane_base + (size_t)(unsigned)sA[j]);
        }
#pragma unroll
        for (int j = 0; j < 8; ++j) {
          a0 += lo16f(uu[j].x);
          a1 += hi16f(uu[j].x);
          a2 += lo16f(uu[j].y);
          a3 += hi16f(uu[j].y);
        }
#pragma unroll
        for (int j = 0; j < 8; ++j) sA[j] = sB[j];
      }
      float dv = dinv[node];
      float o0 = a0 * dv, o1 = a1 * dv, o2 = a2 * dv, o3 = a3 * dv;
      if constexpr (FINAL) {
        o0 += bias[s * CS + cb];
        o1 += bias[s * CS + cb + 1];
        o2 += bias[s * CS + cb + 2];
        o3 += bias[s * CS + cb + 3];
        f32x4 o = {o0, o1, o2, o3};
        *(f32x4*)&((float*)outv)[(size_t)node * C + s * CS + cb] = o;
      } else {
        u16x4 ob = {f2bf_rne(o0), f2bf_rne(o1), f2bf_rne(o2), f2bf_rne(o3)};
        *(unsigned long long*)&((unsigned short*)outv)[(size_t)node * C + s * CS + cb] =
            __builtin_bit_cast(unsigned long long, ob);
      }
      if constexpr (STATS) {
        ssum[0] += o0;
        ssum[1] += o1;
        ssum[2] += o2;
        ssum[3] += o3;
        sq[0] += o0 * o0;
        sq[1] += o1 * o1;
        sq[2] += o2 * o2;
        sq[3] += o3 * o3;
      }
    }
  }

  if constexpr (STATS) {
    __shared__ float red[256][8];
    const int t = threadIdx.x;
#pragma unroll
    for (int m = 0; m < 4; ++m) {
      red[t][m] = ssum[m];
      red[t][4 + m] = sq[m];
    }
    __syncthreads();
    if (t < LPE) {
      float a[4] = {0.f, 0.f, 0.f, 0.f}, b[4] = {0.f, 0.f, 0.f, 0.f};
      for (int k = t; k < 256; k += LPE) {
#pragma unroll
        for (int m = 0; m < 4; ++m) {
          a[m] += red[k][m];
          b[m] += red[k][4 + m];
        }
      }
#pragma unroll
      for (int m = 0; m < 4; ++m) {
        atomicAdd(&stat[s * CS + t * 4 + m], a[m]);
        atomicAdd(&stat[C + s * CS + t * 4 + m], b[m]);
      }
    }
  }
}

// ================= BN finalize =================

template <int C>
__global__ void bn_finalize(const float* __restrict__ stat, const float* __restrict__ gamma,
                            const float* __restrict__ beta, float* __restrict__ ss, int N) {
  int c = threadIdx.x;
  if (c >= C) return;
  float mu = stat[c] / (float)N;
  float var = stat[C + c] / (float)N - mu * mu;
  float rs = rsqrtf(var + BN_EPS);
  float sc = gamma[c] * rs;
  ss[c] = sc;
  ss[C + c] = beta[c] - mu * sc;
}

// ================= launch =================

extern "C" void kernel_launch(void* const* d_in, const int* in_sizes, int n_in, void* d_out,
                              int out_size, void* d_ws, size_t ws_size, hipStream_t stream) {
  const float* x = (const float*)d_in[0];
  const int* ei = (const int*)d_in[1];
  const float* W1 = (const float*)d_in[2];
  const float* gamma1 = (const float*)d_in[4];
  const float* beta1 = (const float*)d_in[5];
  const float* W2 = (const float*)d_in[6];
  const float* gamma2 = (const float*)d_in[8];
  const float* beta2 = (const float*)d_in[9];
  const float* W3 = (const float*)d_in[10];
  const float* b3 = (const float*)d_in[11];
  float* out = (float*)d_out;

  const int N = in_sizes[0] / IN_CH;  // 100000
  const int E = in_sizes[1] / 2;      // 1600000
  const int* e_src = ei;
  const int* e_dst = ei + E;
  const int nbk = (N + 255) >> 8;  // 391

  char* ws = (char*)d_ws;
  size_t off = 0;
  auto alloc = [&](size_t bytes) {
    size_t r = off;
    off += (bytes + 1023) & ~(size_t)1023;
    return r;
  };
  int* bcnt = (int*)(ws + alloc(NBK_MAX * 4));
  int* boff = (int*)(ws + alloc((NBK_MAX + 1) * 4));
  int* gcur = (int*)(ws + alloc(NBK_MAX * 4));
  unsigned* part = (unsigned*)(ws + alloc((size_t)E * 4));
  int* offs = (int*)(ws + alloc((size_t)(N + 1) * 4));
  int* srcs = (int*)(ws + alloc(((size_t)E + 32) * 4));  // +32: speculative reads
  float* dinv = (float*)(ws + alloc((size_t)N * 4));
  unsigned short* Wt1h = (unsigned short*)(ws + alloc(256 * 128 * 2));
  unsigned short* Wt1l = (unsigned short*)(ws + alloc(256 * 128 * 2));
  unsigned short* Wt2h = (unsigned short*)(ws + alloc(128 * 64 * 2));
  unsigned short* Wt2l = (unsigned short*)(ws + alloc(128 * 64 * 2));
  unsigned short* Wt3h = (unsigned short*)(ws + alloc(64 * 64 * 2));
  unsigned short* Wt3l = (unsigned short*)(ws + alloc(64 * 64 * 2));
  float* stat1 = (float*)(ws + alloc(256 * 4));
  float* stat2 = (float*)(ws + alloc(128 * 4));
  float* ss1 = (float*)(ws + alloc(256 * 4));
  float* ss2 = (float*)(ws + alloc(128 * 4));
  unsigned short* g = (unsigned short*)(ws + alloc((size_t)N * 128 * 2));   // sliced GEMM out
  unsigned short* hb = (unsigned short*)(ws + alloc((size_t)N * 128 * 2));  // row-major agg out

  hipMemsetAsync(bcnt, 0, NBK_MAX * 4, stream);
  hipMemsetAsync(stat1, 0, 256 * 4, stream);
  hipMemsetAsync(stat2, 0, 128 * 4, stream);

  bucket_hist<<<2048, 256, 0, stream>>>(e_dst, bcnt, E, nbk);
  bucket_scan<<<1, 512, 0, stream>>>(bcnt, boff, gcur, E, nbk);
  partition<<<(E + 4095) / 4096, 256, 0, stream>>>(e_src, e_dst, gcur, part, E, nbk);
  bucket_csr<<<nbk, 256, 0, stream>>>(part, boff, offs, srcs, dinv, N, E);

  wprep<<<(256 * 128 + 255) / 256, 256, 0, stream>>>(W1, Wt1h, Wt1l, 256, 128);
  wprep<<<(128 * 64 + 255) / 256, 256, 0, stream>>>(W2, Wt2h, Wt2l, 128, 64);
  wprep<<<(64 * 64 + 255) / 256, 256, 0, stream>>>(W3, Wt3h, Wt3l, 64, 64);

  const int gM = (N + 127) / 128;   // 782
  const int nch = (N + 127) / 128;  // node chunks
  const dim3 gAgg1(8, nch);         // layer 1: 8 slices
  const dim3 gAgg2(4, nch);         // layers 2/3: 4 slices

  // ---- layer 1: 256 -> 128 ----
  mfma_gemm<256, 128, 8, false, false><<<gM, 256, 0, stream>>>(x, Wt1h, Wt1l, nullptr, dinv, g,
                                                               N);
  agg_slice<128, 8, true, false><<<gAgg1, 256, 0, stream>>>(g, offs, srcs, dinv, nullptr, hb,
                                                            stat1, N);
  bn_finalize<128><<<1, 128, 0, stream>>>(stat1, gamma1, beta1, ss1, N);

  // ---- layer 2: 128 -> 64 (BN+ReLU fused into A staging, A = bf16 hb) ----
  mfma_gemm<128, 64, 4, true, true><<<gM, 256, 0, stream>>>(hb, Wt2h, Wt2l, ss1, dinv, g, N);
  agg_slice<64, 4, true, false><<<gAgg2, 256, 0, stream>>>(g, offs, srcs, dinv, nullptr, hb,
                                                           stat2, N);
  bn_finalize<64><<<1, 64, 0, stream>>>(stat2, gamma2, beta2, ss2, N);

  // ---- layer 3: 64 -> 64 ----
  mfma_gemm<64, 64, 4, true, true><<<gM, 256, 0, stream>>>(hb, Wt3h, Wt3l, ss2, dinv, g, N);
  agg_slice<64, 4, false, true><<<gAgg2, 256, 0, stream>>>(g, offs, srcs, dinv, b3, out, nullptr,
                                                           N);
}

// Round 14
// 376.462 us; speedup vs baseline: 1.1532x; 1.1334x over previous
//
#include <hip/hip_runtime.h>
#include <cstdint>
#include <cstddef>

#define IN_CH 256

constexpr float BN_EPS = 1e-5f;

using u16x4 = __attribute__((ext_vector_type(4))) unsigned short;
using u16x8 = __attribute__((ext_vector_type(8))) unsigned short;
using bf16x8 = __attribute__((ext_vector_type(8))) short;
using f32x4 = __attribute__((ext_vector_type(4))) float;

__device__ __forceinline__ unsigned short f2bf_rne(float x) {
  unsigned u = __builtin_bit_cast(unsigned, x);
  unsigned r = u + 0x7FFFu + ((u >> 16) & 1u);
  return (unsigned short)(r >> 16);
}
__device__ __forceinline__ float bf2f(unsigned short h) {
  unsigned u = ((unsigned)h) << 16;
  return __builtin_bit_cast(float, u);
}
__device__ __forceinline__ float lo16f(unsigned u) {
  return __builtin_bit_cast(float, u << 16);
}
__device__ __forceinline__ float hi16f(unsigned u) {
  return __builtin_bit_cast(float, u & 0xffff0000u);
}

// ================= CSR build: bucketed counting sort, coalesced IO =================
// pack = (dst & 255) << 17 | src   (src < 2^17)

#define NBK_MAX 400

__global__ __launch_bounds__(256) void bucket_hist(const int* __restrict__ dst,
                                                   int* __restrict__ bcnt, int E, int nbk) {
  __shared__ int c[NBK_MAX];
  for (int j = threadIdx.x; j < nbk; j += 256) c[j] = 0;
  __syncthreads();
  for (int i = blockIdx.x * 256 + threadIdx.x; i < E; i += gridDim.x * 256)
    atomicAdd(&c[dst[i] >> 8], 1);
  __syncthreads();
  for (int j = threadIdx.x; j < nbk; j += 256)
    if (c[j]) atomicAdd(&bcnt[j], c[j]);
}

__global__ void bucket_scan(const int* __restrict__ bcnt, int* __restrict__ boff,
                            int* __restrict__ gcur, int E, int nbk) {
  __shared__ int lds[512];
  int t = threadIdx.x;
  int v = (t < nbk) ? bcnt[t] : 0;
  lds[t] = v;
  __syncthreads();
  for (int s = 1; s < 512; s <<= 1) {
    int x = (t >= s) ? lds[t - s] : 0;
    __syncthreads();
    lds[t] += x;
    __syncthreads();
  }
  if (t < nbk) {
    boff[t] = lds[t] - v;
    gcur[t] = lds[t] - v;
  }
  if (t == 0) boff[nbk] = E;
}

__global__ __launch_bounds__(256) void partition(const int* __restrict__ src,
                                                 const int* __restrict__ dst,
                                                 int* __restrict__ gcur,
                                                 unsigned* __restrict__ part, int E, int nbk) {
  __shared__ int cnt[NBK_MAX];
  __shared__ int base[NBK_MAX];
  const int t = threadIdx.x;
  for (int j = t; j < nbk; j += 256) cnt[j] = 0;
  __syncthreads();
  const int e0 = blockIdx.x * 4096;
  unsigned mypk[16];
  int mybk[16];
#pragma unroll
  for (int u = 0; u < 16; ++u) {
    int e = e0 + u * 256 + t;
    if (e < E) {
      int d = dst[e];
      mypk[u] = (unsigned)src[e] | ((unsigned)(d & 255) << 17);
      mybk[u] = d >> 8;
      atomicAdd(&cnt[mybk[u]], 1);
    } else {
      mybk[u] = -1;
    }
  }
  __syncthreads();
  for (int j = t; j < nbk; j += 256) {
    int c = cnt[j];
    base[j] = c ? atomicAdd(&gcur[j], c) : 0;
    cnt[j] = 0;
  }
  __syncthreads();
#pragma unroll
  for (int u = 0; u < 16; ++u) {
    if (mybk[u] >= 0) {
      int r = atomicAdd(&cnt[mybk[u]], 1);
      part[base[mybk[u]] + r] = mypk[u];
    }
  }
}

// emits srcs as BYTE OFFSETS (row * 32, CS=16 bf16 rows) for the agg kernels
__global__ __launch_bounds__(256) void bucket_csr(const unsigned* __restrict__ part,
                                                  const int* __restrict__ boff,
                                                  int* __restrict__ offs, int* __restrict__ srcs,
                                                  float* __restrict__ dinv, int N, int E) {
  __shared__ unsigned pk[8192];
  __shared__ int ssrc[8192];
  __shared__ int cnt[256];
  __shared__ int offl[256];
  __shared__ int cur[256];
  const int b = blockIdx.x;
  const int t = threadIdx.x;
  const int e0 = boff[b];
  int ne = boff[b + 1] - e0;
  if (ne > 8192) ne = 8192;
  cnt[t] = 0;
  __syncthreads();
  for (int i = t; i < ne; i += 256) {
    unsigned v = part[e0 + i];
    pk[i] = v;
    atomicAdd(&cnt[v >> 17], 1);
  }
  __syncthreads();
  int vv = cnt[t];
  offl[t] = vv;
  __syncthreads();
  for (int s = 1; s < 256; s <<= 1) {
    int x = (t >= s) ? offl[t - s] : 0;
    __syncthreads();
    offl[t] += x;
    __syncthreads();
  }
  int excl = offl[t] - vv;
  cur[t] = excl;
  __syncthreads();
  for (int i = t; i < ne; i += 256) {
    unsigned p = pk[i];
    int dl = p >> 17;
    int r = atomicAdd(&cur[dl], 1);
    ssrc[r] = (int)(p & 0x1FFFF) << 5;  // byte offset, row stride 32B
  }
  __syncthreads();
  for (int i = t; i < ne; i += 256) srcs[e0 + i] = ssrc[i];
  int node = b * 256 + t;
  if (node < N) {
    offs[node] = e0 + excl;
    dinv[node] = rsqrtf((float)(vv + 1));
  }
  if (b == gridDim.x - 1 && t == 0) offs[N] = E;
}

// ================= weight prep: transpose + hi/lo bf16 split =================

__global__ void wprep(const float* __restrict__ W, unsigned short* __restrict__ hi,
                      unsigned short* __restrict__ lo, int K, int N) {
  int i = blockIdx.x * 256 + threadIdx.x;
  if (i >= K * N) return;
  int k = i / N, n = i - k * N;
  float v = W[i];
  unsigned short h = f2bf_rne(v);
  hi[(size_t)n * K + k] = h;
  lo[(size_t)n * K + k] = f2bf_rne(v - bf2f(h));
}

// ================= MFMA GEMM =================
// A: fp32 (ABF16=false) or bf16 row-major (ABF16=true).
// Out (bf16) written COLUMN-SLICED: [SLICES][M][BN/SLICES]

template <int K, int BN, int SLICES, bool BNRELU, bool ABF16>
__global__ __launch_bounds__(256) void mfma_gemm(const void* __restrict__ Av,
                                                 const unsigned short* __restrict__ Bt_hi,
                                                 const unsigned short* __restrict__ Bt_lo,
                                                 const float* __restrict__ ss,
                                                 const float* __restrict__ dinv,
                                                 unsigned short* __restrict__ Out, int M) {
  constexpr int BM = 128;
  constexpr int CS = BN / SLICES;  // = 16
  __shared__ unsigned short Ah[BM * 32];
  __shared__ unsigned short Al[BM * 32];
  __shared__ unsigned short Bh[BN * 32];
  __shared__ unsigned short Bl[BN * 32];

  const int tid = threadIdx.x;
  const int wave = tid >> 6;
  const int lane = tid & 63;
  const int lg = lane >> 4;
  const int lr = lane & 15;
  const int row0 = blockIdx.x * BM;

  f32x4 acc[2][BN / 16];
#pragma unroll
  for (int f = 0; f < 2; ++f)
#pragma unroll
    for (int j = 0; j < BN / 16; ++j) acc[f][j] = (f32x4){0.f, 0.f, 0.f, 0.f};

  for (int k0 = 0; k0 < K; k0 += 32) {
    __syncthreads();
#pragma unroll
    for (int it = 0; it < 4; ++it) {
      int m = it * 32 + (tid >> 3);
      int c2 = tid & 7;
      float vv[4] = {0.f, 0.f, 0.f, 0.f};
      if constexpr (ABF16) {
        if (row0 + m < M) {
          u16x4 r = *(const u16x4*)&(
              (const unsigned short*)Av)[(size_t)(row0 + m) * K + k0 + c2 * 4];
#pragma unroll
          for (int i = 0; i < 4; ++i) vv[i] = bf2f(r[i]);
        }
      } else {
        if (row0 + m < M) {
          float4 v = *(const float4*)&((const float*)Av)[(size_t)(row0 + m) * K + k0 + c2 * 4];
          vv[0] = v.x;
          vv[1] = v.y;
          vv[2] = v.z;
          vv[3] = v.w;
        }
      }
      if constexpr (BNRELU) {
        int kk = k0 + c2 * 4;
        float4 sc = *(const float4*)&ss[kk];
        float4 sh = *(const float4*)&ss[K + kk];
        vv[0] = fmaxf(0.f, fmaf(vv[0], sc.x, sh.x));
        vv[1] = fmaxf(0.f, fmaf(vv[1], sc.y, sh.y));
        vv[2] = fmaxf(0.f, fmaf(vv[2], sc.z, sh.z));
        vv[3] = fmaxf(0.f, fmaf(vv[3], sc.w, sh.w));
      }
      u16x4 h4, l4;
#pragma unroll
      for (int i = 0; i < 4; ++i) {
        unsigned short h = f2bf_rne(vv[i]);
        h4[i] = h;
        l4[i] = f2bf_rne(vv[i] - bf2f(h));
      }
      int pr = (m >> 1) & 3;
      int base = m * 32 + (((c2 >> 1) ^ pr) * 8) + (c2 & 1) * 4;
      *(u16x4*)&Ah[base] = h4;
      *(u16x4*)&Al[base] = l4;
    }
#pragma unroll
    for (int it = 0; it < BN / 64; ++it) {
      int n = it * 64 + (tid >> 2);
      int c = tid & 3;
      int pr = (n >> 1) & 3;
      int base = n * 32 + ((c ^ pr) * 8);
      *(u16x8*)&Bh[base] = *(const u16x8*)&Bt_hi[(size_t)n * K + k0 + c * 8];
      *(u16x8*)&Bl[base] = *(const u16x8*)&Bt_lo[(size_t)n * K + k0 + c * 8];
    }
    __syncthreads();

    bf16x8 afh[2], afl[2];
#pragma unroll
    for (int f = 0; f < 2; ++f) {
      int m = wave * 32 + f * 16 + lr;
      int pr = (m >> 1) & 3;
      int base = m * 32 + ((lg ^ pr) * 8);
      afh[f] = *(const bf16x8*)&Ah[base];
      afl[f] = *(const bf16x8*)&Al[base];
    }
#pragma unroll
    for (int j = 0; j < BN / 16; ++j) {
      int n = j * 16 + lr;
      int pr = (n >> 1) & 3;
      int base = n * 32 + ((lg ^ pr) * 8);
      bf16x8 bh = *(const bf16x8*)&Bh[base];
      bf16x8 bl = *(const bf16x8*)&Bl[base];
#pragma unroll
      for (int f = 0; f < 2; ++f) {
        acc[f][j] = __builtin_amdgcn_mfma_f32_16x16x32_bf16(afh[f], bh, acc[f][j], 0, 0, 0);
        acc[f][j] = __builtin_amdgcn_mfma_f32_16x16x32_bf16(afl[f], bh, acc[f][j], 0, 0, 0);
        acc[f][j] = __builtin_amdgcn_mfma_f32_16x16x32_bf16(afh[f], bl, acc[f][j], 0, 0, 0);
      }
    }
  }

  // epilogue: scale by dinv, store bf16 column-sliced [SLICES][M][CS]
#pragma unroll
  for (int f = 0; f < 2; ++f) {
#pragma unroll
    for (int r4 = 0; r4 < 4; ++r4) {
      int r = row0 + wave * 32 + f * 16 + lg * 4 + r4;
      if (r >= M) continue;
      float dv = dinv[r];
#pragma unroll
      for (int j = 0; j < BN / 16; ++j) {
        int c = j * 16 + lr;
        int slice = c / CS;
        int wi = c % CS;
        Out[((size_t)slice * M + r) * CS + wi] = f2bf_rne(acc[f][j][r4] * dv);
      }
    }
  }
}

// ================= sliced aggregation, node-per-group, 8-deep pipelined =================
// g column-sliced [NSLICE][N][CS=16] bf16 (row stride 32B). Block = (slice, 128-node
// chunk), 4 waves. 8-lane groups own one node each (dword = 2ch per lane); 8-edge
// predicated batches with next-batch srcs prefetch; ALL loads/stores cached (NT
// regressed r10: srcs in dependent chain must stay L2-resident; LPE=4 regressed r13:
// divergence + L2 pressure; 2-deep pipeline + padding regressed r12).
// srcs holds BYTE offsets. FINAL=false: out bf16 row-major; FINAL=true: fp32 (+bias).

template <int C, int NSLICE, bool STATS, bool FINAL>
__global__ __launch_bounds__(256) void agg_slice(const unsigned short* __restrict__ g,
                                                 const int* __restrict__ offs,
                                                 const int* __restrict__ srcsb,
                                                 const float* __restrict__ dinv,
                                                 const float* __restrict__ bias,
                                                 void* __restrict__ outv,
                                                 float* __restrict__ stat, int N) {
  constexpr int CS = C / NSLICE;  // 16
  constexpr int LPE = 8;          // lanes per node-group, 2ch (4B) per lane
  constexpr int NPW = 64 / LPE;   // 8 nodes per wave per iter
  constexpr int T = 4;            // 4 iters x 4 waves x 8 = 128 nodes per block
  const int s = blockIdx.x;       // slice
  const int w = threadIdx.x >> 6;
  const int lane = threadIdx.x & 63;
  const int gi = lane >> 3;   // node sub-index
  const int ch2 = lane & 7;   // channel pair within slice
  const char* lane_base = (const char*)(g + (size_t)s * N * CS) + ch2 * 4;
  const int cb = ch2 * 2;

  float sx = 0.f, sy = 0.f, qx = 0.f, qy = 0.f;

#pragma unroll
  for (int it = 0; it < T; ++it) {
    int node = blockIdx.y * 128 + it * (4 * NPW) + w * NPW + gi;
    if (node < N) {
      unsigned u = *(const unsigned*)(lane_base + (size_t)node * (CS * 2));
      float ax = lo16f(u);
      float ay = hi16f(u);

      const int e0 = offs[node], e1 = offs[node + 1];
      const int nb = (e1 - e0 + 7) >> 3;
      int sA[8], sB[8];
#pragma unroll
      for (int j = 0; j < 8; ++j) sA[j] = srcsb[e0 + j];  // padded alloc: safe
      for (int b = 0; b < nb; ++b) {
        const int base = e0 + b * 8;
#pragma unroll
        for (int j = 0; j < 8; ++j) sB[j] = srcsb[base + 8 + j];  // prefetch next
        unsigned uu[8];
#pragma unroll
        for (int j = 0; j < 8; ++j) {
          uu[j] = 0u;
          if (base + j < e1) uu[j] = *(const unsigned*)(lane_base + (size_t)(unsigned)sA[j]);
        }
#pragma unroll
        for (int j = 0; j < 8; ++j) {
          ax += lo16f(uu[j]);
          ay += hi16f(uu[j]);
        }
#pragma unroll
        for (int j = 0; j < 8; ++j) sA[j] = sB[j];
      }
      float dv = dinv[node];
      float ox = ax * dv, oy = ay * dv;
      if constexpr (FINAL) {
        ox += bias[s * CS + cb];
        oy += bias[s * CS + cb + 1];
        *(float2*)&((float*)outv)[(size_t)node * C + s * CS + cb] = (float2){ox, oy};
      } else {
        unsigned ob = (unsigned)f2bf_rne(ox) | ((unsigned)f2bf_rne(oy) << 16);
        ((unsigned*)outv)[((size_t)node * C + s * CS + cb) >> 1] = ob;
      }
      if constexpr (STATS) {
        sx += ox;
        sy += oy;
        qx += ox * ox;
        qy += oy * oy;
      }
    }
  }

  if constexpr (STATS) {
    __shared__ float red[256][4];
    red[threadIdx.x][0] = sx;
    red[threadIdx.x][1] = sy;
    red[threadIdx.x][2] = qx;
    red[threadIdx.x][3] = qy;
    __syncthreads();
    if (threadIdx.x < LPE) {
      float a0 = 0.f, a1 = 0.f, a2 = 0.f, a3 = 0.f;
      for (int k = threadIdx.x; k < 256; k += LPE) {
        a0 += red[k][0];
        a1 += red[k][1];
        a2 += red[k][2];
        a3 += red[k][3];
      }
      atomicAdd(&stat[s * CS + threadIdx.x * 2], a0);
      atomicAdd(&stat[s * CS + threadIdx.x * 2 + 1], a1);
      atomicAdd(&stat[C + s * CS + threadIdx.x * 2], a2);
      atomicAdd(&stat[C + s * CS + threadIdx.x * 2 + 1], a3);
    }
  }
}

// ================= BN finalize =================

template <int C>
__global__ void bn_finalize(const float* __restrict__ stat, const float* __restrict__ gamma,
                            const float* __restrict__ beta, float* __restrict__ ss, int N) {
  int c = threadIdx.x;
  if (c >= C) return;
  float mu = stat[c] / (float)N;
  float var = stat[C + c] / (float)N - mu * mu;
  float rs = rsqrtf(var + BN_EPS);
  float sc = gamma[c] * rs;
  ss[c] = sc;
  ss[C + c] = beta[c] - mu * sc;
}

// ================= launch =================

extern "C" void kernel_launch(void* const* d_in, const int* in_sizes, int n_in, void* d_out,
                              int out_size, void* d_ws, size_t ws_size, hipStream_t stream) {
  const float* x = (const float*)d_in[0];
  const int* ei = (const int*)d_in[1];
  const float* W1 = (const float*)d_in[2];
  const float* gamma1 = (const float*)d_in[4];
  const float* beta1 = (const float*)d_in[5];
  const float* W2 = (const float*)d_in[6];
  const float* gamma2 = (const float*)d_in[8];
  const float* beta2 = (const float*)d_in[9];
  const float* W3 = (const float*)d_in[10];
  const float* b3 = (const float*)d_in[11];
  float* out = (float*)d_out;

  const int N = in_sizes[0] / IN_CH;  // 100000
  const int E = in_sizes[1] / 2;      // 1600000
  const int* e_src = ei;
  const int* e_dst = ei + E;
  const int nbk = (N + 255) >> 8;  // 391

  char* ws = (char*)d_ws;
  size_t off = 0;
  auto alloc = [&](size_t bytes) {
    size_t r = off;
    off += (bytes + 1023) & ~(size_t)1023;
    return r;
  };
  int* bcnt = (int*)(ws + alloc(NBK_MAX * 4));
  int* boff = (int*)(ws + alloc((NBK_MAX + 1) * 4));
  int* gcur = (int*)(ws + alloc(NBK_MAX * 4));
  unsigned* part = (unsigned*)(ws + alloc((size_t)E * 4));
  int* offs = (int*)(ws + alloc((size_t)(N + 1) * 4));
  int* srcs = (int*)(ws + alloc(((size_t)E + 32) * 4));  // +32: speculative reads
  float* dinv = (float*)(ws + alloc((size_t)N * 4));
  unsigned short* Wt1h = (unsigned short*)(ws + alloc(256 * 128 * 2));
  unsigned short* Wt1l = (unsigned short*)(ws + alloc(256 * 128 * 2));
  unsigned short* Wt2h = (unsigned short*)(ws + alloc(128 * 64 * 2));
  unsigned short* Wt2l = (unsigned short*)(ws + alloc(128 * 64 * 2));
  unsigned short* Wt3h = (unsigned short*)(ws + alloc(64 * 64 * 2));
  unsigned short* Wt3l = (unsigned short*)(ws + alloc(64 * 64 * 2));
  float* stat1 = (float*)(ws + alloc(256 * 4));
  float* stat2 = (float*)(ws + alloc(128 * 4));
  float* ss1 = (float*)(ws + alloc(256 * 4));
  float* ss2 = (float*)(ws + alloc(128 * 4));
  unsigned short* g = (unsigned short*)(ws + alloc((size_t)N * 128 * 2));   // sliced GEMM out
  unsigned short* hb = (unsigned short*)(ws + alloc((size_t)N * 128 * 2));  // row-major agg out

  hipMemsetAsync(bcnt, 0, NBK_MAX * 4, stream);
  hipMemsetAsync(stat1, 0, 256 * 4, stream);
  hipMemsetAsync(stat2, 0, 128 * 4, stream);

  bucket_hist<<<2048, 256, 0, stream>>>(e_dst, bcnt, E, nbk);
  bucket_scan<<<1, 512, 0, stream>>>(bcnt, boff, gcur, E, nbk);
  partition<<<(E + 4095) / 4096, 256, 0, stream>>>(e_src, e_dst, gcur, part, E, nbk);
  bucket_csr<<<nbk, 256, 0, stream>>>(part, boff, offs, srcs, dinv, N, E);

  wprep<<<(256 * 128 + 255) / 256, 256, 0, stream>>>(W1, Wt1h, Wt1l, 256, 128);
  wprep<<<(128 * 64 + 255) / 256, 256, 0, stream>>>(W2, Wt2h, Wt2l, 128, 64);
  wprep<<<(64 * 64 + 255) / 256, 256, 0, stream>>>(W3, Wt3h, Wt3l, 64, 64);

  const int gM = (N + 127) / 128;   // 782
  const int nch = (N + 127) / 128;  // node chunks
  const dim3 gAgg1(8, nch);         // layer 1: 8 slices
  const dim3 gAgg2(4, nch);         // layers 2/3: 4 slices

  // ---- layer 1: 256 -> 128 ----
  mfma_gemm<256, 128, 8, false, false><<<gM, 256, 0, stream>>>(x, Wt1h, Wt1l, nullptr, dinv, g,
                                                               N);
  agg_slice<128, 8, true, false><<<gAgg1, 256, 0, stream>>>(g, offs, srcs, dinv, nullptr, hb,
                                                            stat1, N);
  bn_finalize<128><<<1, 128, 0, stream>>>(stat1, gamma1, beta1, ss1, N);

  // ---- layer 2: 128 -> 64 (BN+ReLU fused into A staging, A = bf16 hb) ----
  mfma_gemm<128, 64, 4, true, true><<<gM, 256, 0, stream>>>(hb, Wt2h, Wt2l, ss1, dinv, g, N);
  agg_slice<64, 4, true, false><<<gAgg2, 256, 0, stream>>>(g, offs, srcs, dinv, nullptr, hb,
                                                           stat2, N);
  bn_finalize<64><<<1, 64, 0, stream>>>(stat2, gamma2, beta2, ss2, N);

  // ---- layer 3: 64 -> 64 ----
  mfma_gemm<64, 64, 4, true, true><<<gM, 256, 0, stream>>>(hb, Wt3h, Wt3l, ss2, dinv, g, N);
  agg_slice<64, 4, false, true><<<gAgg2, 256, 0, stream>>>(g, offs, srcs, dinv, b3, out, nullptr,
                                                           N);
}